// Round 2
// baseline (441.526 us; speedup 1.0000x reference)
//
#include <hip/hip_runtime.h>

// GQA_22436909154699: softmax over a size-1 axis == 1.0, so the reference
// reduces to  out[bl, g*512+h*64+d] = (x @ Wkv + bkv)[bl, g*128+64+d].
// => one (16384 x 2048) @ (2048 x 256) GEMM (v-cols only) + broadcast x8.
// R2: latency-bound fix — BK=64 dbuf LDS (B only), raw lgkmcnt barrier
// (loads stay in flight across it), A direct global->VGPR, fast prep_b.

#define EMBED 2048
#define BM 32
#define BK 64
#define KITERS (EMBED / BK)    // 32
#define BUF_HALFS (256 * 64)   // one B buffer: 32 KB

typedef _Float16 half8 __attribute__((ext_vector_type(8)));
typedef float f32x4 __attribute__((ext_vector_type(4)));

#define VS 260  // fp32 V-tile row stride for epilogue (16B-aligned, 2-way banks)

// XOR-swizzled 16B-chunk offset (in halfs) inside one B buffer.
// row in [0,256) (= n), c in [0,8) (= 16B chunk along k). 2-way banks max.
__device__ __forceinline__ int bchunk(int row, int c) {
  return row * 64 + ((c ^ (row & 7)) * 8);
}

#define ASM_BARRIER() asm volatile("s_waitcnt lgkmcnt(0)\ns_barrier" ::: "memory")

// ---- pre-pass: Bt[n][k] (f16) = Wkv[k][vcol(n)], vcol(n)=(n>>6)*128+64+(n&63)
// 256 blocks x 256 threads, 8 coalesced loads/thread, no LDS.
__global__ __launch_bounds__(256) void prep_b(const float* __restrict__ Wkv,
                                              _Float16* __restrict__ Bt) {
  const int t = threadIdx.x;
  const int kb = blockIdx.x * 8;  // 256 blocks cover k = 0..2047
  const int vcol = ((t >> 6) * 128) + 64 + (t & 63);
  float v[8];
#pragma unroll
  for (int i = 0; i < 8; ++i) v[i] = Wkv[(size_t)(kb + i) * 512 + vcol];
  half8 h;
#pragma unroll
  for (int i = 0; i < 8; ++i) h[i] = (_Float16)v[i];
  *(half8*)&Bt[(size_t)t * EMBED + kb] = h;
}

// ---- main: V = x @ Bt^T + bias, broadcast-write
__global__ __launch_bounds__(256, 2) void gqa_main(
    const float* __restrict__ x, const _Float16* __restrict__ Bt,
    const float* __restrict__ bkv, float* __restrict__ out) {
  __shared__ _Float16 Bs[2 * BUF_HALFS];  // 64 KB: double-buffered B slab

  const int tid = threadIdx.x;
  const int wave = tid >> 6;
  const int lane = tid & 63;
  const int lm = lane & 15;
  const int lq = lane >> 4;
  const int r0 = blockIdx.x * BM;

  // B staging: thread t covers rows (t>>3) + p*32, chunk c = t&7 (128-B segs)
  const int srow = tid >> 3;
  const int sc = tid & 7;
  const _Float16* bgp = Bt + (size_t)srow * EMBED + sc * 8;
  int bso[8];
#pragma unroll
  for (int p = 0; p < 8; ++p) bso[p] = bchunk(srow + p * 32, sc);

  // A direct-from-global fragment base: lane -> row r0 + mi*16 + lm, k = lq*8+j
  const float* ag0 = x + (size_t)(r0 + lm) * EMBED + lq * 8;

  half8 breg[2][8];
  f32x4 acc[2][4] = {};

#define LOADB(kt, R)                                                       \
  {                                                                        \
    const _Float16* p_ = bgp + (kt) * BK;                                  \
    _Pragma("unroll") for (int i_ = 0; i_ < 8; ++i_)                       \
        R[i_] = *(const half8*)(p_ + (size_t)i_ * 32 * EMBED);             \
  }
#define STOREB(R, buf)                                                     \
  {                                                                        \
    _Float16* b_ = Bs + (buf)*BUF_HALFS;                                   \
    _Pragma("unroll") for (int i_ = 0; i_ < 8; ++i_)                       \
        *(half8*)(b_ + bso[i_]) = R[i_];                                   \
  }

  LOADB(0, breg[0]);
  STOREB(breg[0], 0);
  LOADB(1, breg[1]);
  ASM_BARRIER();  // buf0 ready; slab-1 loads stay in flight

  for (int kt = 0; kt < KITERS; ++kt) {
    const int cur = kt & 1;

    // A loads for this iter (global, 128-B segments, L1-shared across waves)
    f32x4 a[2][2][2];  // [mi][ksub][lo/hi]
#pragma unroll
    for (int mi = 0; mi < 2; ++mi)
#pragma unroll
      for (int ks = 0; ks < 2; ++ks) {
        const float* p = ag0 + (size_t)mi * 16 * EMBED + kt * BK + ks * 32;
        a[mi][ks][0] = *(const f32x4*)p;
        a[mi][ks][1] = *(const f32x4*)(p + 4);
      }

    // store slab kt+1 (loaded last iter) into the other buffer; prefetch kt+2
    if (kt + 1 < KITERS) STOREB(breg[(kt + 1) & 1], 1 - cur);
    if (kt + 2 < KITERS) LOADB(kt + 2, breg[kt & 1]);

    // compute slab kt from Bs[cur]
    const _Float16* bb = Bs + cur * BUF_HALFS;
#pragma unroll
    for (int ks = 0; ks < 2; ++ks) {
      half8 af[2];
#pragma unroll
      for (int mi = 0; mi < 2; ++mi)
#pragma unroll
        for (int j = 0; j < 4; ++j) {
          af[mi][j] = (_Float16)a[mi][ks][0][j];
          af[mi][4 + j] = (_Float16)a[mi][ks][1][j];
        }
#pragma unroll
      for (int ni = 0; ni < 4; ++ni) {
        const int row = wave * 64 + ni * 16 + lm;
        half8 bf = *(const half8*)(bb + bchunk(row, ks * 4 + lq));
        acc[0][ni] =
            __builtin_amdgcn_mfma_f32_16x16x32_f16(af[0], bf, acc[0][ni], 0, 0, 0);
        acc[1][ni] =
            __builtin_amdgcn_mfma_f32_16x16x32_f16(af[1], bf, acc[1][ni], 0, 0, 0);
      }
    }
    ASM_BARRIER();  // lgkmcnt-only: breg global loads remain in flight
  }

  // epilogue: bias + V tile to LDS (C/D: col = lane&15, row = lq*4 + r)
  float* Vs = (float*)Bs;  // overlay: 32 x VS fp32 = 33280 B <= 64 KB
#pragma unroll
  for (int ni = 0; ni < 4; ++ni) {
    const int ncol = wave * 64 + ni * 16 + lm;
    const float bias = bkv[((ncol >> 6) * 128) + 64 + (ncol & 63)];
#pragma unroll
    for (int mi = 0; mi < 2; ++mi) {
      f32x4 v = acc[mi][ni];
#pragma unroll
      for (int r = 0; r < 4; ++r) {
        Vs[(mi * 16 + lq * 4 + r) * VS + ncol] = v[r] + bias;
      }
    }
  }
  __syncthreads();

  // broadcast: out[r0+m][ch] = V[m][(ch>>9)*64 + (ch&63)], float4-coalesced
  f32x4* out4 = (f32x4*)out;
  const size_t obase = (size_t)r0 * 512;
#pragma unroll 4
  for (int i = 0; i < 64; ++i) {
    const int f = i * 256 + tid;
    const int m = f >> 9;
    const int c4 = f & 511;
    const int g = c4 >> 7;
    const int d4 = c4 & 15;
    out4[obase + (size_t)f] = *(const f32x4*)&Vs[m * VS + g * 64 + d4 * 4];
  }
}

extern "C" void kernel_launch(void* const* d_in, const int* in_sizes, int n_in,
                              void* d_out, int out_size, void* d_ws, size_t ws_size,
                              hipStream_t stream) {
  const float* x = (const float*)d_in[0];
  // d_in[1] = Wq, d_in[2] = bq : dead code (softmax over size-1 axis == 1)
  const float* Wkv = (const float*)d_in[3];
  const float* bkv = (const float*)d_in[4];
  float* out = (float*)d_out;
  _Float16* Bt = (_Float16*)d_ws;  // 256*2048 f16 = 1 MB scratch

  prep_b<<<256, 256, 0, stream>>>(Wkv, Bt);
  gqa_main<<<(4 * 4096) / BM, 256, 0, stream>>>(x, Bt, bkv, out);
}

// Round 3
// 319.692 us; speedup vs baseline: 1.3811x; 1.3811x over previous
//
#include <hip/hip_runtime.h>

// GQA_22436909154699: softmax over a size-1 axis == 1.0, so the reference
// reduces to  out[bl, g*512+h*64+d] = (x @ Wkv + bkv)[bl, g*128+64+d].
// => one (16384 x 2048) @ (2048 x 256) GEMM (v-cols only) + broadcast x8.
// R3: R2 pipeline minus the spill — NO runtime-indexed register arrays
// (unroll-by-2, named prefetch sets), A+B both reg-double-buffered,
// one lgkmcnt-only barrier per K-iter (global loads stay in flight).

#define EMBED 2048
#define BM 32
#define BK 32
#define KITERS (EMBED / BK)  // 64
#define BUFH (256 * BK)      // one B buffer: 8192 halfs = 16 KB
#define VS 260               // epilogue fp32 V-tile stride (<=2-way banks)

typedef _Float16 half8 __attribute__((ext_vector_type(8)));
typedef float f32x4 __attribute__((ext_vector_type(4)));

#define ASM_BARRIER() asm volatile("s_waitcnt lgkmcnt(0)\ns_barrier" ::: "memory")

// ---- pre-pass: Bt[n][k] (f16) = Wkv[k][vcol(n)], vcol(n)=(n>>6)*128+64+(n&63)
__global__ __launch_bounds__(256) void prep_b(const float* __restrict__ Wkv,
                                              _Float16* __restrict__ Bt) {
  const int t = threadIdx.x;
  const int kb = blockIdx.x * 8;  // 256 blocks cover k = 0..2047
  const int vcol = ((t >> 6) * 128) + 64 + (t & 63);
  float v[8];
#pragma unroll
  for (int i = 0; i < 8; ++i) v[i] = Wkv[(size_t)(kb + i) * 512 + vcol];
  half8 h;
#pragma unroll
  for (int i = 0; i < 8; ++i) h[i] = (_Float16)v[i];
  *(half8*)&Bt[(size_t)t * EMBED + kb] = h;
}

__device__ __forceinline__ half8 cvt8(f32x4 lo, f32x4 hi) {
  half8 r;
#pragma unroll
  for (int j = 0; j < 4; ++j) {
    r[j] = (_Float16)lo[j];
    r[4 + j] = (_Float16)hi[j];
  }
  return r;
}

// ---- main: V = x @ Bt^T + bias, broadcast-write
__global__ __launch_bounds__(256, 3) void gqa_main(
    const float* __restrict__ x, const _Float16* __restrict__ Bt,
    const float* __restrict__ bkv, float* __restrict__ out) {
  __shared__ __align__(16) char smem[BM * VS * 4];  // 33280 B >= 2x16KB bufs
  _Float16* Bs0 = (_Float16*)smem;
  _Float16* Bs1 = Bs0 + BUFH;
  float* Vs = (float*)smem;  // epilogue overlay

  const int tid = threadIdx.x;
  const int wave = tid >> 6;
  const int lane = tid & 63;
  const int lm = lane & 15;
  const int lq = lane >> 4;
  const int r0 = blockIdx.x * BM;

  // B staging: thread t -> rows (t>>2)+p*64 (p=0..3), 16B chunk c=t&3
  const int srow = tid >> 2, sc = tid & 3;
  const _Float16* bgp = Bt + (size_t)srow * EMBED + sc * 8;
  int bofs[4];
#pragma unroll
  for (int p = 0; p < 4; ++p)
    bofs[p] = (srow + p * 64) * BK + ((sc ^ (srow & 3)) * 8);

  // B fragment read offsets (row = wave*64+ni*16+lm, chunk = lq)
  int bro[4];
#pragma unroll
  for (int ni = 0; ni < 4; ++ni) {
    const int row = wave * 64 + ni * 16 + lm;
    bro[ni] = row * BK + ((lq ^ (row & 3)) * 8);
  }

  // A direct-from-global: lane -> row r0+mi*16+lm, k = kt*32 + lq*8 + j
  const float* ag = x + (size_t)(r0 + lm) * EMBED + lq * 8;

  half8 bA[4], bB[4];        // B prefetch sets (named -> stays in VGPRs)
  f32x4 aA[2][2], aB[2][2];  // A prefetch sets [mi][lo/hi]
  f32x4 acc[2][4] = {};

#define LOADB(kt, R)                                                     \
  {                                                                      \
    const _Float16* p_ = bgp + (kt) * BK;                                \
    _Pragma("unroll") for (int i_ = 0; i_ < 4; ++i_)                     \
        R[i_] = *(const half8*)(p_ + (size_t)i_ * 64 * EMBED);           \
  }
#define LOADA(kt, R)                                                     \
  {                                                                      \
    _Pragma("unroll") for (int mi_ = 0; mi_ < 2; ++mi_) {                \
      const float* p_ = ag + (size_t)mi_ * 16 * EMBED + (kt) * BK;       \
      R[mi_][0] = *(const f32x4*)p_;                                     \
      R[mi_][1] = *(const f32x4*)(p_ + 4);                               \
    }                                                                    \
  }
#define STOREB(R, base)                                                  \
  {                                                                      \
    _Pragma("unroll") for (int i_ = 0; i_ < 4; ++i_)                     \
        *(half8*)((base) + bofs[i_]) = R[i_];                            \
  }
#define MFMA8(base, af0, af1)                                            \
  {                                                                      \
    _Pragma("unroll") for (int ni_ = 0; ni_ < 4; ++ni_) {                \
      half8 bf_ = *(const half8*)((base) + bro[ni_]);                    \
      acc[0][ni_] = __builtin_amdgcn_mfma_f32_16x16x32_f16(              \
          af0, bf_, acc[0][ni_], 0, 0, 0);                               \
      acc[1][ni_] = __builtin_amdgcn_mfma_f32_16x16x32_f16(              \
          af1, bf_, acc[1][ni_], 0, 0, 0);                               \
    }                                                                    \
  }

  // prologue: slab0 -> bA -> Bs0; slab1 -> bB; A slabs 0,1 -> aA,aB
  LOADB(0, bA);
  LOADB(1, bB);
  LOADA(0, aA);
  LOADA(1, aB);
  STOREB(bA, Bs0);  // compiler waits vmcnt for bA only; rest stay in flight
  ASM_BARRIER();

  for (int kt = 0; kt < KITERS; kt += 2) {
    // ---- even iter: compute slab kt from Bs0
    STOREB(bB, Bs1);  // slab kt+1 (kt+1 <= 63 always)
    {
      half8 af0 = cvt8(aA[0][0], aA[0][1]);
      half8 af1 = cvt8(aA[1][0], aA[1][1]);
      if (kt + 2 < KITERS) {
        LOADB(kt + 2, bA);
        LOADA(kt + 2, aA);
      }
      MFMA8(Bs0, af0, af1);
    }
    ASM_BARRIER();  // lgkm-only: prefetch global loads remain in flight

    // ---- odd iter: compute slab kt+1 from Bs1
    if (kt + 2 < KITERS) STOREB(bA, Bs0);  // slab kt+2
    {
      half8 af0 = cvt8(aB[0][0], aB[0][1]);
      half8 af1 = cvt8(aB[1][0], aB[1][1]);
      if (kt + 3 < KITERS) {
        LOADB(kt + 3, bB);
        LOADA(kt + 3, aB);
      }
      MFMA8(Bs1, af0, af1);
    }
    ASM_BARRIER();
  }

  // epilogue: bias + V tile to LDS (C/D: col = lane&15, row = lq*4 + r)
#pragma unroll
  for (int ni = 0; ni < 4; ++ni) {
    const int ncol = wave * 64 + ni * 16 + lm;
    const float bias = bkv[((ncol >> 6) * 128) + 64 + (ncol & 63)];
#pragma unroll
    for (int mi = 0; mi < 2; ++mi) {
      f32x4 v = acc[mi][ni];
#pragma unroll
      for (int r = 0; r < 4; ++r) {
        Vs[(mi * 16 + lq * 4 + r) * VS + ncol] = v[r] + bias;
      }
    }
  }
  __syncthreads();

  // broadcast: out[r0+m][ch] = V[m][(ch>>9)*64 + (ch&63)], float4-coalesced
  f32x4* out4 = (f32x4*)out;
  const size_t obase = (size_t)r0 * 512;
#pragma unroll 4
  for (int i = 0; i < 64; ++i) {
    const int f = i * 256 + tid;
    const int m = f >> 9;
    const int c4 = f & 511;
    const int g = c4 >> 7;
    const int d4 = c4 & 15;
    out4[obase + (size_t)f] = *(const f32x4*)&Vs[m * VS + g * 64 + d4 * 4];
  }
}

extern "C" void kernel_launch(void* const* d_in, const int* in_sizes, int n_in,
                              void* d_out, int out_size, void* d_ws, size_t ws_size,
                              hipStream_t stream) {
  const float* x = (const float*)d_in[0];
  // d_in[1] = Wq, d_in[2] = bq : dead code (softmax over size-1 axis == 1)
  const float* Wkv = (const float*)d_in[3];
  const float* bkv = (const float*)d_in[4];
  float* out = (float*)d_out;
  _Float16* Bt = (_Float16*)d_ws;  // 256*2048 f16 = 1 MB scratch

  prep_b<<<256, 256, 0, stream>>>(Wkv, Bt);
  gqa_main<<<(4 * 4096) / BM, 256, 0, stream>>>(x, Bt, bkv, out);
}